// Round 1
// baseline (5259.472 us; speedup 1.0000x reference)
//
#include <hip/hip_runtime.h>
#include <stdint.h>
#include <stddef.h>

#define NB 1024
#define TB 1024
#define D_IN 6
#define UNITS 64
#define WIDTH 128
#define DOUT 6
#define EPSF 1e-8f
#define SPB 16          // samples per block
#define LDK0 104        // c0 row stride (ushorts); cols: [0..5]=xn, [6,7]=0, [8..71]=h, [72..95]=0
#define LDK 136         // c-buffer row stride; cols 0..127 used

typedef short v8s __attribute__((ext_vector_type(8)));
typedef float v4f __attribute__((ext_vector_type(4)));

#define MFMA16(A,Bf,C) __builtin_amdgcn_mfma_f32_16x16x32_bf16((A),(Bf),(C),0,0,0)

__device__ __forceinline__ unsigned short f2bf(float x){
  uint32_t u = __float_as_uint(x);
  u += 0x7FFFu + ((u >> 16) & 1u);
  return (unsigned short)(u >> 16);
}
__device__ __forceinline__ float bf2f(unsigned short s){
  return __uint_as_float(((uint32_t)s) << 16);
}
__device__ __forceinline__ float fast_tanh(float v){
  float e = __expf(2.0f * v);
  return 1.0f - 2.0f / (e + 1.0f);
}

union FragU { v8s v; unsigned short u[8]; };

__device__ __forceinline__ void make_frag(const float* vals, v8s& hv, v8s& lv){
  FragU H, L;
  #pragma unroll
  for (int j = 0; j < 8; j++){
    unsigned short h = f2bf(vals[j]);
    H.u[j] = h;
    L.u[j] = f2bf(vals[j] - bf2f(h));
  }
  hv = H.v; lv = L.v;
}

__device__ __forceinline__ void split_write(unsigned short* hi, unsigned short* lo, int idx, float v){
  unsigned short h = f2bf(v);
  hi[idx] = h;
  lo[idx] = f2bf(v - bf2f(h));
}

__global__ __launch_bounds__(256, 1) void lmsc_kernel(
    const float* __restrict__ x, const float* __restrict__ initF,
    const float* __restrict__ w10, const float* __restrict__ b10,
    const float* __restrict__ w20, const float* __restrict__ b20,
    const float* __restrict__ w11, const float* __restrict__ b11,
    const float* __restrict__ w21, const float* __restrict__ b21,
    const float* __restrict__ w12, const float* __restrict__ b12,
    const float* __restrict__ w22, const float* __restrict__ b22,
    const float* __restrict__ wa, const float* __restrict__ ba,
    const float* __restrict__ wb, const float* __restrict__ bb,
    const float* __restrict__ wo,
    float* __restrict__ outs, float* __restrict__ alph)
{
  // ---- LDS (static, 158784 B total <= 163840) ----
  __shared__ __attribute__((aligned(16))) unsigned short c0h[SPB*LDK0];
  __shared__ __attribute__((aligned(16))) unsigned short c0l[SPB*LDK0];
  __shared__ __attribute__((aligned(16))) unsigned short cAh[SPB*LDK];
  __shared__ __attribute__((aligned(16))) unsigned short cAl[SPB*LDK];
  __shared__ __attribute__((aligned(16))) float Hs[SPB*UNITS];
  __shared__ __attribute__((aligned(16))) float preA[SPB*UNITS];
  __shared__ __attribute__((aligned(16))) float preB[SPB*UNITS];
  __shared__ __attribute__((aligned(16))) float nrm[SPB];
  __shared__ __attribute__((aligned(16))) unsigned short BlL1[4*16*64*8];  // [wave][kf*4+nt*2+br][lane][8]
  __shared__ __attribute__((aligned(16))) unsigned short BlL2[4*16*64*8];

  const int tid = threadIdx.x;
  const int wv = tid >> 6;       // wave 0..3
  const int ln = tid & 63;
  const int mn = ln & 15;        // n (B,D cols) / m (A rows)
  const int qd = ln >> 4;        // quad
  const int q8 = qd * 8;
  const int sgbase = (int)blockIdx.x * SPB;

  float tmp[8];

  // ---------------- one-time: load weight B-fragments ----------------
  // L0: K padded to 96 in c0-column space; hi+lo in regs
  v8s B0h[3][2][2], B0l[3][2][2];
  #pragma unroll
  for (int kf = 0; kf < 3; kf++)
    #pragma unroll
    for (int nt = 0; nt < 2; nt++)
      #pragma unroll
      for (int br = 0; br < 2; br++){
        const float* W = br ? w20 : w10;
        int n = wv*32 + nt*16 + mn;
        #pragma unroll
        for (int j = 0; j < 8; j++){
          int k = kf*32 + q8 + j;
          int r = (k < 6) ? k : ((k >= 8 && k < 72) ? (k - 2) : -1);
          tmp[j] = (r >= 0) ? W[r*WIDTH + n] : 0.0f;
        }
        make_frag(tmp, B0h[kf][nt][br], B0l[kf][nt][br]);
      }

  // L1: hi in regs, lo in LDS
  v8s B1h[4][2][2];
  #pragma unroll
  for (int kf = 0; kf < 4; kf++)
    #pragma unroll
    for (int nt = 0; nt < 2; nt++)
      #pragma unroll
      for (int br = 0; br < 2; br++){
        const float* W = br ? w21 : w11;
        int n = wv*32 + nt*16 + mn;
        #pragma unroll
        for (int j = 0; j < 8; j++){
          int k = kf*32 + q8 + j;
          tmp[j] = W[k*WIDTH + n];
        }
        v8s lv;
        make_frag(tmp, B1h[kf][nt][br], lv);
        *(v8s*)(BlL1 + (((wv*16 + kf*4 + nt*2 + br)*64 + ln) << 3)) = lv;
      }

  // L2: hi in regs, lo in LDS
  v8s B2h[4][2][2];
  #pragma unroll
  for (int kf = 0; kf < 4; kf++)
    #pragma unroll
    for (int nt = 0; nt < 2; nt++)
      #pragma unroll
      for (int br = 0; br < 2; br++){
        const float* W = br ? w22 : w12;
        int n = wv*32 + nt*16 + mn;
        #pragma unroll
        for (int j = 0; j < 8; j++){
          int k = kf*32 + q8 + j;
          tmp[j] = W[k*WIDTH + n];
        }
        v8s lv;
        make_frag(tmp, B2h[kf][nt][br], lv);
        *(v8s*)(BlL2 + (((wv*16 + kf*4 + nt*2 + br)*64 + ln) << 3)) = lv;
      }

  // wa (waves 0,1) / wb (waves 2,3): hi+lo in regs
  const float* Wab = (wv < 2) ? wa : wb;
  const float* bab = (wv < 2) ? ba : bb;
  const int ubase = (wv & 1) * 32;
  v8s Bah[4][2], Bal[4][2];
  #pragma unroll
  for (int kf = 0; kf < 4; kf++)
    #pragma unroll
    for (int nt = 0; nt < 2; nt++){
      int n = ubase + nt*16 + mn;
      #pragma unroll
      for (int j = 0; j < 8; j++){
        int k = kf*32 + q8 + j;
        tmp[j] = Wab[k*UNITS + n];
      }
      make_frag(tmp, Bah[kf][nt], Bal[kf][nt]);
    }

  // wout on wave 3 only (K=64, N=6 padded to 16)
  v8s Woh0, Wol0, Woh1, Wol1;
  if (wv == 3){
    #pragma unroll
    for (int j = 0; j < 8; j++){
      int k = q8 + j;
      tmp[j] = (mn < DOUT) ? wo[k*DOUT + mn] : 0.0f;
    }
    make_frag(tmp, Woh0, Wol0);
    #pragma unroll
    for (int j = 0; j < 8; j++){
      int k = 32 + q8 + j;
      tmp[j] = (mn < DOUT) ? wo[k*DOUT + mn] : 0.0f;
    }
    make_frag(tmp, Woh1, Wol1);
  }

  // biases (per-lane column values)
  float bs0a[2], bs0b[2], bs1a[2], bs1b[2], bs2a[2], bs2b[2], bsab[2];
  #pragma unroll
  for (int nt = 0; nt < 2; nt++){
    int n = wv*32 + nt*16 + mn;
    bs0a[nt] = b10[n]; bs0b[nt] = b20[n];
    bs1a[nt] = b11[n]; bs1b[nt] = b21[n];
    bs2a[nt] = b12[n]; bs2b[nt] = b22[n];
    bsab[nt] = bab[ubase + nt*16 + mn];
  }

  // ---------------- activation init ----------------
  for (int i = tid; i < SPB*LDK0; i += 256){ c0h[i] = 0; c0l[i] = 0; }
  __syncthreads();
  {
    int s = tid >> 4, u0 = (tid & 15) * 4;
    #pragma unroll
    for (int r = 0; r < 4; r++){
      float v = initF[(size_t)(sgbase + s)*(2 + UNITS) + 2 + u0 + r];
      Hs[s*UNITS + u0 + r] = v;
      split_write(c0h, c0l, s*LDK0 + 8 + u0 + r, v);
    }
  }
  // prefetch x(t=0)
  float xv0=0, xv1=0, xv2=0, xv3=0, xv4=0, xv5=0;
  if (wv == 0 && ln < 16){
    const float* xp = x + (size_t)(sgbase + ln)*TB*D_IN;
    xv0 = xp[0]; xv1 = xp[1]; xv2 = xp[2]; xv3 = xp[3]; xv4 = xp[4]; xv5 = xp[5];
  }
  __syncthreads();

  auto wout_phase = [&](int tt){
    v8s ah0 = *(const v8s*)(c0h + mn*LDK0 + 8 + q8);
    v8s al0 = *(const v8s*)(c0l + mn*LDK0 + 8 + q8);
    v8s ah1 = *(const v8s*)(c0h + mn*LDK0 + 40 + q8);
    v8s al1 = *(const v8s*)(c0l + mn*LDK0 + 40 + q8);
    v4f acc = {0.f, 0.f, 0.f, 0.f};
    acc = MFMA16(ah0, Woh0, acc); acc = MFMA16(al0, Woh0, acc); acc = MFMA16(ah0, Wol0, acc);
    acc = MFMA16(ah1, Woh1, acc); acc = MFMA16(al1, Woh1, acc); acc = MFMA16(ah1, Wol1, acc);
    if (mn < DOUT){
      #pragma unroll
      for (int r = 0; r < 4; r++){
        size_t sg = (size_t)(sgbase + qd*4 + r);
        outs[(sg*TB + (size_t)tt)*DOUT + mn] = acc[r];
      }
    }
  };

  // ================= time loop =================
  for (int t = 0; t < TB; t++){
    // ---- P0: x-norm (wave0) + wout for t-1 (wave3) ----
    if (wv == 0 && ln < 16){
      int s = ln;
      float ssum = xv0*xv0 + xv1*xv1 + xv2*xv2 + xv3*xv3 + xv4*xv4 + xv5*xv5;
      float nv = sqrtf(ssum);
      nrm[s] = nv;
      float inv = 1.0f / (nv + EPSF);
      split_write(c0h, c0l, s*LDK0 + 0, xv0*inv);
      split_write(c0h, c0l, s*LDK0 + 1, xv1*inv);
      split_write(c0h, c0l, s*LDK0 + 2, xv2*inv);
      split_write(c0h, c0l, s*LDK0 + 3, xv3*inv);
      split_write(c0h, c0l, s*LDK0 + 4, xv4*inv);
      split_write(c0h, c0l, s*LDK0 + 5, xv5*inv);
      if (t + 1 < TB){
        const float* xp = x + (size_t)(sgbase + s)*TB*D_IN + (size_t)(t + 1)*D_IN;
        xv0 = xp[0]; xv1 = xp[1]; xv2 = xp[2]; xv3 = xp[3]; xv4 = xp[4]; xv5 = xp[5];
      }
    }
    if (wv == 3 && t > 0) wout_phase(t - 1);
    __syncthreads();  // B1

    // ---- L0 ----
    {
      v8s ah[3], al[3];
      #pragma unroll
      for (int kf = 0; kf < 3; kf++){
        ah[kf] = *(const v8s*)(c0h + mn*LDK0 + kf*32 + q8);
        al[kf] = *(const v8s*)(c0l + mn*LDK0 + kf*32 + q8);
      }
      v4f acc[2][2];
      #pragma unroll
      for (int nt = 0; nt < 2; nt++){
        float ba0 = bs0a[nt], bb0 = bs0b[nt];
        acc[nt][0] = (v4f){ba0, ba0, ba0, ba0};
        acc[nt][1] = (v4f){bb0, bb0, bb0, bb0};
      }
      #pragma unroll
      for (int kf = 0; kf < 3; kf++)
        #pragma unroll
        for (int nt = 0; nt < 2; nt++)
          #pragma unroll
          for (int br = 0; br < 2; br++){
            v4f a = acc[nt][br];
            a = MFMA16(ah[kf], B0h[kf][nt][br], a);
            a = MFMA16(al[kf], B0h[kf][nt][br], a);
            a = MFMA16(ah[kf], B0l[kf][nt][br], a);
            acc[nt][br] = a;
          }
      #pragma unroll
      for (int nt = 0; nt < 2; nt++)
        #pragma unroll
        for (int r = 0; r < 4; r++){
          float v1 = fast_tanh(acc[nt][0][r]);
          float v2 = fast_tanh(acc[nt][1][r]);
          split_write(cAh, cAl, (qd*4 + r)*LDK + wv*32 + nt*16 + mn, v1*v2);
        }
    }
    __syncthreads();  // B2

    // ---- L1 ----
    float cv1[2][4];
    {
      v8s ah[4], al[4];
      #pragma unroll
      for (int kf = 0; kf < 4; kf++){
        ah[kf] = *(const v8s*)(cAh + mn*LDK + kf*32 + q8);
        al[kf] = *(const v8s*)(cAl + mn*LDK + kf*32 + q8);
      }
      v4f acc[2][2];
      #pragma unroll
      for (int nt = 0; nt < 2; nt++){
        float ba1 = bs1a[nt], bb1 = bs1b[nt];
        acc[nt][0] = (v4f){ba1, ba1, ba1, ba1};
        acc[nt][1] = (v4f){bb1, bb1, bb1, bb1};
      }
      #pragma unroll
      for (int kf = 0; kf < 4; kf++)
        #pragma unroll
        for (int nt = 0; nt < 2; nt++)
          #pragma unroll
          for (int br = 0; br < 2; br++){
            v8s bl = *(const v8s*)(BlL1 + (((wv*16 + kf*4 + nt*2 + br)*64 + ln) << 3));
            v4f a = acc[nt][br];
            a = MFMA16(ah[kf], B1h[kf][nt][br], a);
            a = MFMA16(al[kf], B1h[kf][nt][br], a);
            a = MFMA16(ah[kf], bl, a);
            acc[nt][br] = a;
          }
      #pragma unroll
      for (int nt = 0; nt < 2; nt++)
        #pragma unroll
        for (int r = 0; r < 4; r++)
          cv1[nt][r] = fast_tanh(acc[nt][0][r]) * fast_tanh(acc[nt][1][r]);
    }
    __syncthreads();  // Br1: everyone done reading c1
    #pragma unroll
    for (int nt = 0; nt < 2; nt++)
      #pragma unroll
      for (int r = 0; r < 4; r++)
        split_write(cAh, cAl, (qd*4 + r)*LDK + wv*32 + nt*16 + mn, cv1[nt][r]);
    __syncthreads();  // B3

    // ---- L2 (last layer: no tanh on branches; g = tanh(x1*x2)) ----
    float cv2[2][4];
    {
      v8s ah[4], al[4];
      #pragma unroll
      for (int kf = 0; kf < 4; kf++){
        ah[kf] = *(const v8s*)(cAh + mn*LDK + kf*32 + q8);
        al[kf] = *(const v8s*)(cAl + mn*LDK + kf*32 + q8);
      }
      v4f acc[2][2];
      #pragma unroll
      for (int nt = 0; nt < 2; nt++){
        float ba2 = bs2a[nt], bb2 = bs2b[nt];
        acc[nt][0] = (v4f){ba2, ba2, ba2, ba2};
        acc[nt][1] = (v4f){bb2, bb2, bb2, bb2};
      }
      #pragma unroll
      for (int kf = 0; kf < 4; kf++)
        #pragma unroll
        for (int nt = 0; nt < 2; nt++)
          #pragma unroll
          for (int br = 0; br < 2; br++){
            v8s bl = *(const v8s*)(BlL2 + (((wv*16 + kf*4 + nt*2 + br)*64 + ln) << 3));
            v4f a = acc[nt][br];
            a = MFMA16(ah[kf], B2h[kf][nt][br], a);
            a = MFMA16(al[kf], B2h[kf][nt][br], a);
            a = MFMA16(ah[kf], bl, a);
            acc[nt][br] = a;
          }
      #pragma unroll
      for (int nt = 0; nt < 2; nt++)
        #pragma unroll
        for (int r = 0; r < 4; r++)
          cv2[nt][r] = fast_tanh(acc[nt][0][r] * acc[nt][1][r]);
    }
    __syncthreads();  // Br2: everyone done reading c2
    #pragma unroll
    for (int nt = 0; nt < 2; nt++)
      #pragma unroll
      for (int r = 0; r < 4; r++)
        split_write(cAh, cAl, (qd*4 + r)*LDK + wv*32 + nt*16 + mn, cv2[nt][r]);
    __syncthreads();  // B4

    // ---- wa/wb ----
    {
      v8s gh[4], gl[4];
      #pragma unroll
      for (int kf = 0; kf < 4; kf++){
        gh[kf] = *(const v8s*)(cAh + mn*LDK + kf*32 + q8);
        gl[kf] = *(const v8s*)(cAl + mn*LDK + kf*32 + q8);
      }
      v4f pacc[2];
      #pragma unroll
      for (int nt = 0; nt < 2; nt++){
        float bv = bsab[nt];
        pacc[nt] = (v4f){bv, bv, bv, bv};
      }
      #pragma unroll
      for (int kf = 0; kf < 4; kf++)
        #pragma unroll
        for (int nt = 0; nt < 2; nt++){
          v4f a = pacc[nt];
          a = MFMA16(gh[kf], Bah[kf][nt], a);
          a = MFMA16(gl[kf], Bah[kf][nt], a);
          a = MFMA16(gh[kf], Bal[kf][nt], a);
          pacc[nt] = a;
        }
      float* dst = (wv < 2) ? preA : preB;
      #pragma unroll
      for (int nt = 0; nt < 2; nt++)
        #pragma unroll
        for (int r = 0; r < 4; r++)
          dst[(qd*4 + r)*UNITS + ubase + nt*16 + mn] = pacc[nt][r];
    }
    __syncthreads();  // B5

    // ---- h update + alpha store ----
    {
      int s = tid >> 4, u0 = (tid & 15) * 4;
      v4f pa = *(const v4f*)(preA + s*UNITS + u0);
      v4f pb = *(const v4f*)(preB + s*UNITS + u0);
      v4f hv = *(const v4f*)(Hs + s*UNITS + u0);
      float nv = nrm[s];
      v4f hn, av;
      #pragma unroll
      for (int i = 0; i < 4; i++){
        float alpha = __expf(pa[i]);
        float beta  = fast_tanh(pb[i]);
        float dec   = __expf(-alpha * nv);
        hn[i] = dec * (hv[i] - beta) + beta;
        av[i] = alpha;
      }
      *(v4f*)(Hs + s*UNITS + u0) = hn;
      #pragma unroll
      for (int i = 0; i < 4; i++)
        split_write(c0h, c0l, s*LDK0 + 8 + u0 + i, hn[i]);
      *(v4f*)(alph + ((size_t)(sgbase + s)*TB + (size_t)t)*UNITS + u0) = av;
    }
    __syncthreads();  // B6
  }

  if (wv == 3) wout_phase(TB - 1);
}

extern "C" void kernel_launch(void* const* d_in, const int* in_sizes, int n_in,
                              void* d_out, int out_size, void* d_ws, size_t ws_size,
                              hipStream_t stream) {
  const float* x    = (const float*)d_in[0];
  const float* iF   = (const float*)d_in[1];
  const float* w10  = (const float*)d_in[2];
  const float* b10  = (const float*)d_in[3];
  const float* w20  = (const float*)d_in[4];
  const float* b20  = (const float*)d_in[5];
  const float* w11  = (const float*)d_in[6];
  const float* b11  = (const float*)d_in[7];
  const float* w21  = (const float*)d_in[8];
  const float* b21  = (const float*)d_in[9];
  const float* w12  = (const float*)d_in[10];
  const float* b12  = (const float*)d_in[11];
  const float* w22  = (const float*)d_in[12];
  const float* b22  = (const float*)d_in[13];
  const float* wa   = (const float*)d_in[14];
  const float* ba   = (const float*)d_in[15];
  const float* wb   = (const float*)d_in[16];
  const float* bb   = (const float*)d_in[17];
  const float* wo   = (const float*)d_in[18];

  float* outs = (float*)d_out;
  float* alph = outs + (size_t)NB*TB*DOUT;

  lmsc_kernel<<<NB/SPB, 256, 0, stream>>>(x, iF,
      w10, b10, w20, b20, w11, b11, w21, b21, w12, b12, w22, b22,
      wa, ba, wb, bb, wo, outs, alph);
}

// Round 2
// 3904.912 us; speedup vs baseline: 1.3469x; 1.3469x over previous
//
#include <hip/hip_runtime.h>
#include <stdint.h>
#include <stddef.h>

#define NB 1024
#define TB 1024
#define D_IN 6
#define UNITS 64
#define WIDTH 128
#define DOUT 6
#define EPSF 1e-8f
#define SPB 16          // samples per block (one 16-row MFMA tile)
#define LDK0 104        // c0 row stride (u16): cols [0..5]=xn, [6,7]=0, [8..71]=h, [72..95]=0, pad
#define LDK 136         // cP/cQ row stride (u16), 272 B = 16B-aligned

typedef short v8s __attribute__((ext_vector_type(8)));
typedef float v4f __attribute__((ext_vector_type(4)));

#define MFMA16(A,Bf,C) __builtin_amdgcn_mfma_f32_16x16x32_bf16((A),(Bf),(C),0,0,0)

// RNE bf16 round (used for one-time weight splitting)
__device__ __forceinline__ unsigned short f2bf_rne(float x){
  uint32_t u = __float_as_uint(x);
  u += 0x7FFFu + ((u >> 16) & 1u);
  return (unsigned short)(u >> 16);
}
__device__ __forceinline__ float bf2f(unsigned short s){
  return __uint_as_float(((uint32_t)s) << 16);
}
// fast tanh: 1 - 2/(e^{2v}+1); exp -> v_exp, div -> rcp+mul
__device__ __forceinline__ float fast_tanh(float v){
  float e = __expf(2.0f * v);
  return 1.0f - __fdividef(2.0f, e + 1.0f);
}

union FragU { v8s v; unsigned short u[8]; };

__device__ __forceinline__ void make_frag(const float* vals, v8s& hv, v8s& lv){
  FragU H, L;
  #pragma unroll
  for (int j = 0; j < 8; j++){
    unsigned short h = f2bf_rne(vals[j]);
    H.u[j] = h;
    L.u[j] = f2bf_rne(vals[j] - bf2f(h));
  }
  hv = H.v; lv = L.v;
}

// cheap hi/lo split write: RTZ hi, exact residual, RTZ lo (err ~2^-16 rel)
__device__ __forceinline__ void split_write(unsigned short* hi, unsigned short* lo, int idx, float v){
  uint32_t u = __float_as_uint(v);
  float d = v - __uint_as_float(u & 0xFFFF0000u);
  hi[idx] = (unsigned short)(u >> 16);
  lo[idx] = (unsigned short)(__float_as_uint(d) >> 16);
}

__global__ __launch_bounds__(512, 2) void lmsc_kernel(
    const float* __restrict__ x, const float* __restrict__ initF,
    const float* __restrict__ w10, const float* __restrict__ b10,
    const float* __restrict__ w20, const float* __restrict__ b20,
    const float* __restrict__ w11, const float* __restrict__ b11,
    const float* __restrict__ w21, const float* __restrict__ b21,
    const float* __restrict__ w12, const float* __restrict__ b12,
    const float* __restrict__ w22, const float* __restrict__ b22,
    const float* __restrict__ wa, const float* __restrict__ ba,
    const float* __restrict__ wb, const float* __restrict__ bb,
    const float* __restrict__ wo,
    float* __restrict__ outs, float* __restrict__ alph)
{
  // ---- LDS: 159,360 B total ----
  __shared__ __attribute__((aligned(16))) unsigned short BlL1[4*8*2*64*8]; // [kf][ct][br][lane][8] lo-frags L1
  __shared__ __attribute__((aligned(16))) unsigned short BlL2[4*8*2*64*8];
  __shared__ __attribute__((aligned(16))) unsigned short c0h[SPB*LDK0];
  __shared__ __attribute__((aligned(16))) unsigned short c0l[SPB*LDK0];
  __shared__ __attribute__((aligned(16))) unsigned short cPh[SPB*LDK];
  __shared__ __attribute__((aligned(16))) unsigned short cPl[SPB*LDK];
  __shared__ __attribute__((aligned(16))) unsigned short cQh[SPB*LDK];
  __shared__ __attribute__((aligned(16))) unsigned short cQl[SPB*LDK];
  __shared__ __attribute__((aligned(16))) float Hs[SPB*UNITS];
  __shared__ __attribute__((aligned(16))) float nrm[2][SPB];

  // preA/preB alias the cQ region (dead when phase D writes them; barriers order all accesses)
  float* preA = (float*)cQh;   // needs 4096 B <= 8704 B
  float* preB = (float*)cQl;

  const int tid = threadIdx.x;
  const int wv = tid >> 6;       // wave 0..7
  const int ln = tid & 63;
  const int mn = ln & 15;
  const int qd = ln >> 4;
  const int q8 = qd * 8;
  const int ct = wv;             // column tile for WIDTH=128 layers
  const int n  = ct * 16 + mn;   // absolute column
  const int sgbase = (int)blockIdx.x * SPB;

  float tmp[8];

  // ---------------- one-time weight fragments ----------------
  // L0: hi+lo in regs; K mapped through c0 columns (xn at 0..5, h at 8..71)
  v8s B0h[3][2], B0l[3][2];
  #pragma unroll
  for (int kf = 0; kf < 3; kf++)
    #pragma unroll
    for (int br = 0; br < 2; br++){
      const float* W = br ? w20 : w10;
      #pragma unroll
      for (int j = 0; j < 8; j++){
        int k = kf*32 + q8 + j;
        int r = (k < 6) ? k : ((k >= 8 && k < 72) ? (k - 2) : -1);
        tmp[j] = (r >= 0) ? W[r*WIDTH + n] : 0.0f;
      }
      make_frag(tmp, B0h[kf][br], B0l[kf][br]);
    }

  // L1: hi in regs, lo -> LDS (indexed by column tile, no duplication)
  v8s B1h[4][2];
  #pragma unroll
  for (int kf = 0; kf < 4; kf++)
    #pragma unroll
    for (int br = 0; br < 2; br++){
      const float* W = br ? w21 : w11;
      #pragma unroll
      for (int j = 0; j < 8; j++)
        tmp[j] = W[(kf*32 + q8 + j)*WIDTH + n];
      v8s lv;
      make_frag(tmp, B1h[kf][br], lv);
      *(v8s*)(BlL1 + ((((kf*8 + ct)*2 + br)*64 + ln) << 3)) = lv;
    }

  // L2: hi in regs, lo -> LDS
  v8s B2h[4][2];
  #pragma unroll
  for (int kf = 0; kf < 4; kf++)
    #pragma unroll
    for (int br = 0; br < 2; br++){
      const float* W = br ? w22 : w12;
      #pragma unroll
      for (int j = 0; j < 8; j++)
        tmp[j] = W[(kf*32 + q8 + j)*WIDTH + n];
      v8s lv;
      make_frag(tmp, B2h[kf][br], lv);
      *(v8s*)(BlL2 + ((((kf*8 + ct)*2 + br)*64 + ln) << 3)) = lv;
    }

  // wa (waves 0-3) / wb (waves 4-7): hi+lo in regs
  const float* Wab = (wv < 4) ? wa : wb;
  const int uab = (wv & 3) * 16 + mn;
  v8s Bah[4], Bal[4];
  #pragma unroll
  for (int kf = 0; kf < 4; kf++){
    #pragma unroll
    for (int j = 0; j < 8; j++)
      tmp[j] = Wab[(kf*32 + q8 + j)*UNITS + uab];
    make_frag(tmp, Bah[kf], Bal[kf]);
  }
  const float bsab = ((wv < 4) ? ba : bb)[uab];

  // wout on wave 7 (K=64 over h, N=6 padded to 16)
  v8s Woh0, Wol0, Woh1, Wol1;
  if (wv == 7){
    #pragma unroll
    for (int j = 0; j < 8; j++)
      tmp[j] = (mn < DOUT) ? wo[(q8 + j)*DOUT + mn] : 0.0f;
    make_frag(tmp, Woh0, Wol0);
    #pragma unroll
    for (int j = 0; j < 8; j++)
      tmp[j] = (mn < DOUT) ? wo[(32 + q8 + j)*DOUT + mn] : 0.0f;
    make_frag(tmp, Woh1, Wol1);
  }

  const float bs0a = b10[n], bs0b = b20[n];
  const float bs1a = b11[n], bs1b = b21[n];
  const float bs2a = b12[n], bs2b = b22[n];

  // ---------------- activation init ----------------
  for (int i = tid; i < SPB*LDK0; i += 512){ c0h[i] = 0; c0l[i] = 0; }
  __syncthreads();
  {
    int s = tid >> 5, u0 = (tid & 31) * 2;
    #pragma unroll
    for (int r = 0; r < 2; r++){
      float v = initF[(size_t)(sgbase + s)*(2 + UNITS) + 2 + u0 + r];
      Hs[s*UNITS + u0 + r] = v;
      split_write(c0h, c0l, s*LDK0 + 8 + u0 + r, v);
    }
  }
  float xv0=0, xv1=0, xv2=0, xv3=0, xv4=0, xv5=0;
  if (tid < 16){
    const float* xp = x + (size_t)(sgbase + tid)*TB*D_IN;
    float a0=xp[0], a1=xp[1], a2=xp[2], a3=xp[3], a4=xp[4], a5=xp[5];
    float nv = sqrtf(a0*a0 + a1*a1 + a2*a2 + a3*a3 + a4*a4 + a5*a5);
    nrm[0][tid] = nv;
    float inv = 1.0f / (nv + EPSF);
    split_write(c0h, c0l, tid*LDK0 + 0, a0*inv);
    split_write(c0h, c0l, tid*LDK0 + 1, a1*inv);
    split_write(c0h, c0l, tid*LDK0 + 2, a2*inv);
    split_write(c0h, c0l, tid*LDK0 + 3, a3*inv);
    split_write(c0h, c0l, tid*LDK0 + 4, a4*inv);
    split_write(c0h, c0l, tid*LDK0 + 5, a5*inv);
    xv0 = xp[6]; xv1 = xp[7]; xv2 = xp[8]; xv3 = xp[9]; xv4 = xp[10]; xv5 = xp[11];  // x(t=1)
  }
  __syncthreads();

  auto wout_phase = [&](int tt){
    v8s ah0 = *(const v8s*)(c0h + mn*LDK0 + 8 + q8);
    v8s al0 = *(const v8s*)(c0l + mn*LDK0 + 8 + q8);
    v8s ah1 = *(const v8s*)(c0h + mn*LDK0 + 40 + q8);
    v8s al1 = *(const v8s*)(c0l + mn*LDK0 + 40 + q8);
    v4f acc = {0.f, 0.f, 0.f, 0.f};
    acc = MFMA16(ah0, Woh0, acc); acc = MFMA16(al0, Woh0, acc); acc = MFMA16(ah0, Wol0, acc);
    acc = MFMA16(ah1, Woh1, acc); acc = MFMA16(al1, Woh1, acc); acc = MFMA16(ah1, Wol1, acc);
    if (mn < DOUT){
      #pragma unroll
      for (int r = 0; r < 4; r++){
        size_t sg = (size_t)(sgbase + qd*4 + r);
        outs[(sg*TB + (size_t)tt)*DOUT + mn] = acc[r];
      }
    }
  };

  // ================= time loop (5 barriers/step) =================
  for (int t = 0; t < TB; t++){
    // ---- Phase A: L0 (c0 -> cP); wave7 also wout(t-1) ----
    {
      v8s ah[3], al[3];
      #pragma unroll
      for (int kf = 0; kf < 3; kf++){
        ah[kf] = *(const v8s*)(c0h + mn*LDK0 + kf*32 + q8);
        al[kf] = *(const v8s*)(c0l + mn*LDK0 + kf*32 + q8);
      }
      v4f acc0 = {bs0a, bs0a, bs0a, bs0a};
      v4f acc1 = {bs0b, bs0b, bs0b, bs0b};
      #pragma unroll
      for (int kf = 0; kf < 3; kf++){
        acc0 = MFMA16(ah[kf], B0h[kf][0], acc0);
        acc1 = MFMA16(ah[kf], B0h[kf][1], acc1);
        acc0 = MFMA16(al[kf], B0h[kf][0], acc0);
        acc1 = MFMA16(al[kf], B0h[kf][1], acc1);
        acc0 = MFMA16(ah[kf], B0l[kf][0], acc0);
        acc1 = MFMA16(ah[kf], B0l[kf][1], acc1);
      }
      if (wv == 7 && t > 0) wout_phase(t - 1);
      #pragma unroll
      for (int r = 0; r < 4; r++){
        float v = fast_tanh(acc0[r]) * fast_tanh(acc1[r]);
        split_write(cPh, cPl, (qd*4 + r)*LDK + n, v);
      }
    }
    __syncthreads();  // b1

    // ---- Phase B: L1 (cP -> cQ) ----
    {
      v8s ah[4], al[4];
      #pragma unroll
      for (int kf = 0; kf < 4; kf++){
        ah[kf] = *(const v8s*)(cPh + mn*LDK + kf*32 + q8);
        al[kf] = *(const v8s*)(cPl + mn*LDK + kf*32 + q8);
      }
      v4f acc0 = {bs1a, bs1a, bs1a, bs1a};
      v4f acc1 = {bs1b, bs1b, bs1b, bs1b};
      #pragma unroll
      for (int kf = 0; kf < 4; kf++){
        v8s wl0 = *(const v8s*)(BlL1 + ((((kf*8 + ct)*2 + 0)*64 + ln) << 3));
        v8s wl1 = *(const v8s*)(BlL1 + ((((kf*8 + ct)*2 + 1)*64 + ln) << 3));
        acc0 = MFMA16(ah[kf], B1h[kf][0], acc0);
        acc1 = MFMA16(ah[kf], B1h[kf][1], acc1);
        acc0 = MFMA16(al[kf], B1h[kf][0], acc0);
        acc1 = MFMA16(al[kf], B1h[kf][1], acc1);
        acc0 = MFMA16(ah[kf], wl0, acc0);
        acc1 = MFMA16(ah[kf], wl1, acc1);
      }
      #pragma unroll
      for (int r = 0; r < 4; r++){
        float v = fast_tanh(acc0[r]) * fast_tanh(acc1[r]);
        split_write(cQh, cQl, (qd*4 + r)*LDK + n, v);
      }
    }
    __syncthreads();  // b2

    // ---- Phase C: L2 (cQ -> cP), g = tanh(x1*x2) ----
    {
      v8s ah[4], al[4];
      #pragma unroll
      for (int kf = 0; kf < 4; kf++){
        ah[kf] = *(const v8s*)(cQh + mn*LDK + kf*32 + q8);
        al[kf] = *(const v8s*)(cQl + mn*LDK + kf*32 + q8);
      }
      v4f acc0 = {bs2a, bs2a, bs2a, bs2a};
      v4f acc1 = {bs2b, bs2b, bs2b, bs2b};
      #pragma unroll
      for (int kf = 0; kf < 4; kf++){
        v8s wl0 = *(const v8s*)(BlL2 + ((((kf*8 + ct)*2 + 0)*64 + ln) << 3));
        v8s wl1 = *(const v8s*)(BlL2 + ((((kf*8 + ct)*2 + 1)*64 + ln) << 3));
        acc0 = MFMA16(ah[kf], B2h[kf][0], acc0);
        acc1 = MFMA16(ah[kf], B2h[kf][1], acc1);
        acc0 = MFMA16(al[kf], B2h[kf][0], acc0);
        acc1 = MFMA16(al[kf], B2h[kf][1], acc1);
        acc0 = MFMA16(ah[kf], wl0, acc0);
        acc1 = MFMA16(ah[kf], wl1, acc1);
      }
      #pragma unroll
      for (int r = 0; r < 4; r++){
        float v = fast_tanh(acc0[r] * acc1[r]);
        split_write(cPh, cPl, (qd*4 + r)*LDK + n, v);
      }
    }
    __syncthreads();  // b3

    // ---- Phase D: wa/wb (cP -> preA/preB in cQ region) ----
    {
      v8s gh[4], gl[4];
      #pragma unroll
      for (int kf = 0; kf < 4; kf++){
        gh[kf] = *(const v8s*)(cPh + mn*LDK + kf*32 + q8);
        gl[kf] = *(const v8s*)(cPl + mn*LDK + kf*32 + q8);
      }
      v4f p = {bsab, bsab, bsab, bsab};
      #pragma unroll
      for (int kf = 0; kf < 4; kf++){
        p = MFMA16(gh[kf], Bah[kf], p);
        p = MFMA16(gl[kf], Bah[kf], p);
        p = MFMA16(gh[kf], Bal[kf], p);
      }
      float* dst = (wv < 4) ? preA : preB;
      #pragma unroll
      for (int r = 0; r < 4; r++)
        dst[(qd*4 + r)*UNITS + uab] = p[r];
    }
    __syncthreads();  // b4

    // ---- Phase E: h update + alpha store + xn(t+1) + x prefetch ----
    {
      int s = tid >> 5, u0 = (tid & 31) * 2;
      float nv = nrm[t & 1][s];
      float av0, av1;
      {
        float pa = preA[s*UNITS + u0], pb = preB[s*UNITS + u0];
        float h  = Hs[s*UNITS + u0];
        float alpha = __expf(pa);
        float beta  = fast_tanh(pb);
        float dec   = __expf(-alpha * nv);
        float hn = dec * (h - beta) + beta;
        Hs[s*UNITS + u0] = hn;
        split_write(c0h, c0l, s*LDK0 + 8 + u0, hn);
        av0 = alpha;
      }
      {
        float pa = preA[s*UNITS + u0 + 1], pb = preB[s*UNITS + u0 + 1];
        float h  = Hs[s*UNITS + u0 + 1];
        float alpha = __expf(pa);
        float beta  = fast_tanh(pb);
        float dec   = __expf(-alpha * nv);
        float hn = dec * (h - beta) + beta;
        Hs[s*UNITS + u0 + 1] = hn;
        split_write(c0h, c0l, s*LDK0 + 8 + u0 + 1, hn);
        av1 = alpha;
      }
      float2 av = {av0, av1};
      *(float2*)(alph + ((size_t)(sgbase + s)*TB + (size_t)t)*UNITS + u0) = av;

      if (tid < 16){
        float nv2 = sqrtf(xv0*xv0 + xv1*xv1 + xv2*xv2 + xv3*xv3 + xv4*xv4 + xv5*xv5);
        nrm[(t + 1) & 1][tid] = nv2;
        float inv = 1.0f / (nv2 + EPSF);
        split_write(c0h, c0l, tid*LDK0 + 0, xv0*inv);
        split_write(c0h, c0l, tid*LDK0 + 1, xv1*inv);
        split_write(c0h, c0l, tid*LDK0 + 2, xv2*inv);
        split_write(c0h, c0l, tid*LDK0 + 3, xv3*inv);
        split_write(c0h, c0l, tid*LDK0 + 4, xv4*inv);
        split_write(c0h, c0l, tid*LDK0 + 5, xv5*inv);
        int tn = t + 2; if (tn > TB - 1) tn = TB - 1;
        const float* xp = x + ((size_t)(sgbase + tid)*TB + (size_t)tn)*D_IN;
        xv0 = xp[0]; xv1 = xp[1]; xv2 = xp[2]; xv3 = xp[3]; xv4 = xp[4]; xv5 = xp[5];
      }
    }
    __syncthreads();  // b5
  }

  if (wv == 7) wout_phase(TB - 1);
}

extern "C" void kernel_launch(void* const* d_in, const int* in_sizes, int n_in,
                              void* d_out, int out_size, void* d_ws, size_t ws_size,
                              hipStream_t stream) {
  const float* x    = (const float*)d_in[0];
  const float* iF   = (const float*)d_in[1];
  const float* w10  = (const float*)d_in[2];
  const float* b10  = (const float*)d_in[3];
  const float* w20  = (const float*)d_in[4];
  const float* b20  = (const float*)d_in[5];
  const float* w11  = (const float*)d_in[6];
  const float* b11  = (const float*)d_in[7];
  const float* w21  = (const float*)d_in[8];
  const float* b21  = (const float*)d_in[9];
  const float* w12  = (const float*)d_in[10];
  const float* b12  = (const float*)d_in[11];
  const float* w22  = (const float*)d_in[12];
  const float* b22  = (const float*)d_in[13];
  const float* wa   = (const float*)d_in[14];
  const float* ba   = (const float*)d_in[15];
  const float* wb   = (const float*)d_in[16];
  const float* bb   = (const float*)d_in[17];
  const float* wo   = (const float*)d_in[18];

  float* outs = (float*)d_out;
  float* alph = outs + (size_t)NB*TB*DOUT;

  lmsc_kernel<<<NB/SPB, 512, 0, stream>>>(x, iF,
      w10, b10, w20, b20, w11, b11, w21, b21, w12, b12, w22, b22,
      wa, ba, wb, bb, wo, outs, alph);
}

// Round 3
// 2907.221 us; speedup vs baseline: 1.8091x; 1.3432x over previous
//
#include <hip/hip_runtime.h>
#include <stdint.h>
#include <stddef.h>

#define NB 1024
#define TB 1024
#define D_IN 6
#define UNITS 64
#define WIDTH 128
#define DOUT 6
#define EPSF 1e-8f
#define SPB 16          // samples per block (one 16-row MFMA tile)
#define LDK0 104        // c0 row stride (halfs): [0..5]=xn, [6,7]=0, [8..71]=h, [72..95]=0, pad
#define LDK 136         // cP/cQ/cG row stride (halfs); 272 B, 16B-aligned rows
#define PRE_LD 68       // preA/preB row stride (floats) — +4 pad kills 4-way bank conflict

typedef _Float16 v8h __attribute__((ext_vector_type(8)));
typedef float v4f __attribute__((ext_vector_type(4)));

#define MFMAH(A,Bf,C) __builtin_amdgcn_mfma_f32_16x16x32_f16((A),(Bf),(C),0,0,0)

__device__ __forceinline__ float fast_tanh(float v){
  float e = __expf(2.0f * v);
  return 1.0f - __fdividef(2.0f, e + 1.0f);
}

__device__ __forceinline__ void make_frag1(const float* vals, v8h& hv){
  #pragma unroll
  for (int j = 0; j < 8; j++) hv[j] = (_Float16)vals[j];
}
__device__ __forceinline__ void make_frag2(const float* vals, v8h& hv, v8h& lv){
  #pragma unroll
  for (int j = 0; j < 8; j++){
    _Float16 h = (_Float16)vals[j];
    hv[j] = h;
    lv[j] = (_Float16)(vals[j] - (float)h);
  }
}

__global__ __launch_bounds__(512, 2) void lmsc_kernel(
    const float* __restrict__ x, const float* __restrict__ initF,
    const float* __restrict__ w10, const float* __restrict__ b10,
    const float* __restrict__ w20, const float* __restrict__ b20,
    const float* __restrict__ w11, const float* __restrict__ b11,
    const float* __restrict__ w21, const float* __restrict__ b21,
    const float* __restrict__ w12, const float* __restrict__ b12,
    const float* __restrict__ w22, const float* __restrict__ b22,
    const float* __restrict__ wa, const float* __restrict__ ba,
    const float* __restrict__ wb, const float* __restrict__ bb,
    const float* __restrict__ wo,
    float* __restrict__ outs, float* __restrict__ alph)
{
  // ---- LDS: ~30 KB ----
  __shared__ __attribute__((aligned(16))) _Float16 c0[SPB*LDK0];
  __shared__ __attribute__((aligned(16))) _Float16 cP[SPB*LDK];
  __shared__ __attribute__((aligned(16))) _Float16 cQ[SPB*LDK];
  __shared__ __attribute__((aligned(16))) _Float16 cGh[SPB*LDK];
  __shared__ __attribute__((aligned(16))) _Float16 cGl[SPB*LDK];
  __shared__ __attribute__((aligned(16))) float preA[SPB*PRE_LD];
  __shared__ __attribute__((aligned(16))) float preB[SPB*PRE_LD];
  __shared__ __attribute__((aligned(16))) float nrm[2][SPB];

  const int tid = threadIdx.x;
  const int wv = tid >> 6;       // wave 0..7
  const int ln = tid & 63;
  const int mn = ln & 15;
  const int qd = ln >> 4;
  const int q8 = qd * 8;
  const int n  = wv * 16 + mn;   // absolute column for WIDTH=128 layers
  const int sgbase = (int)blockIdx.x * SPB;

  float tmp[8];

  // ---------------- one-time weight fragments (all in registers) ----------------
  // L0: single fp16; K mapped through c0 columns (xn at 0..5, h at 8..71)
  v8h B0[3][2];
  #pragma unroll
  for (int kf = 0; kf < 3; kf++)
    #pragma unroll
    for (int br = 0; br < 2; br++){
      const float* W = br ? w20 : w10;
      #pragma unroll
      for (int j = 0; j < 8; j++){
        int k = kf*32 + q8 + j;
        int r = (k < 6) ? k : ((k >= 8 && k < 72) ? (k - 2) : -1);
        tmp[j] = (r >= 0) ? W[r*WIDTH + n] : 0.0f;
      }
      make_frag1(tmp, B0[kf][br]);
    }

  // L1, L2: single fp16
  v8h B1[4][2], B2[4][2];
  #pragma unroll
  for (int kf = 0; kf < 4; kf++)
    #pragma unroll
    for (int br = 0; br < 2; br++){
      const float* W = br ? w21 : w11;
      #pragma unroll
      for (int j = 0; j < 8; j++)
        tmp[j] = W[(kf*32 + q8 + j)*WIDTH + n];
      make_frag1(tmp, B1[kf][br]);
      const float* V = br ? w22 : w12;
      #pragma unroll
      for (int j = 0; j < 8; j++)
        tmp[j] = V[(kf*32 + q8 + j)*WIDTH + n];
      make_frag1(tmp, B2[kf][br]);
    }

  // wa (waves 0-3) / wb (waves 4-7): hi+lo fp16 (alpha path — keep 3-term)
  const float* Wab = (wv < 4) ? wa : wb;
  const int uab = (wv & 3) * 16 + mn;
  v8h Bah[4], Bal[4];
  #pragma unroll
  for (int kf = 0; kf < 4; kf++){
    #pragma unroll
    for (int j = 0; j < 8; j++)
      tmp[j] = Wab[(kf*32 + q8 + j)*UNITS + uab];
    make_frag2(tmp, Bah[kf], Bal[kf]);
  }
  const float bsab = ((wv < 4) ? ba : bb)[uab];

  // wout on wave 7 (K=64 over h, N=6 padded to 16): hi+lo fp16
  v8h Woh0, Wol0, Woh1, Wol1;
  if (wv == 7){
    #pragma unroll
    for (int j = 0; j < 8; j++)
      tmp[j] = (mn < DOUT) ? wo[(q8 + j)*DOUT + mn] : 0.0f;
    make_frag2(tmp, Woh0, Wol0);
    #pragma unroll
    for (int j = 0; j < 8; j++)
      tmp[j] = (mn < DOUT) ? wo[(32 + q8 + j)*DOUT + mn] : 0.0f;
    make_frag2(tmp, Woh1, Wol1);
  }

  const float bs0a = b10[n], bs0b = b20[n];
  const float bs1a = b11[n], bs1b = b21[n];
  const float bs2a = b12[n], bs2b = b22[n];

  // ---------------- activation init ----------------
  for (int i = tid; i < SPB*LDK0; i += 512) c0[i] = (_Float16)0.0f;
  __syncthreads();

  // persistent h in registers: thread owns (s = tid>>5, units u0, u0+1)
  const int es = tid >> 5;
  const int eu = (tid & 31) * 2;
  float h0 = initF[(size_t)(sgbase + es)*(2 + UNITS) + 2 + eu];
  float h1 = initF[(size_t)(sgbase + es)*(2 + UNITS) + 2 + eu + 1];
  c0[es*LDK0 + 8 + eu]     = (_Float16)h0;
  c0[es*LDK0 + 8 + eu + 1] = (_Float16)h1;

  float xv0=0, xv1=0, xv2=0, xv3=0, xv4=0, xv5=0;
  if (tid < 16){
    const float* xp = x + (size_t)(sgbase + tid)*TB*D_IN;
    float a0=xp[0], a1=xp[1], a2=xp[2], a3=xp[3], a4=xp[4], a5=xp[5];
    float nv = sqrtf(a0*a0 + a1*a1 + a2*a2 + a3*a3 + a4*a4 + a5*a5);
    nrm[0][tid] = nv;
    float inv = 1.0f / (nv + EPSF);
    c0[tid*LDK0 + 0] = (_Float16)(a0*inv);
    c0[tid*LDK0 + 1] = (_Float16)(a1*inv);
    c0[tid*LDK0 + 2] = (_Float16)(a2*inv);
    c0[tid*LDK0 + 3] = (_Float16)(a3*inv);
    c0[tid*LDK0 + 4] = (_Float16)(a4*inv);
    c0[tid*LDK0 + 5] = (_Float16)(a5*inv);
    xv0 = xp[6]; xv1 = xp[7]; xv2 = xp[8]; xv3 = xp[9]; xv4 = xp[10]; xv5 = xp[11];  // x(t=1)
  }
  __syncthreads();

  auto wout_phase = [&](int tt){
    v8h ah0 = *(const v8h*)(c0 + mn*LDK0 + 8 + q8);
    v8h ah1 = *(const v8h*)(c0 + mn*LDK0 + 40 + q8);
    v4f acc = {0.f, 0.f, 0.f, 0.f};
    acc = MFMAH(ah0, Woh0, acc); acc = MFMAH(ah0, Wol0, acc);
    acc = MFMAH(ah1, Woh1, acc); acc = MFMAH(ah1, Wol1, acc);
    if (mn < DOUT){
      #pragma unroll
      for (int r = 0; r < 4; r++){
        size_t sg = (size_t)(sgbase + qd*4 + r);
        outs[(sg*TB + (size_t)tt)*DOUT + mn] = acc[r];
      }
    }
  };

  // ================= time loop (5 barriers/step) =================
  for (int t = 0; t < TB; t++){
    // ---- Phase A: L0 (c0 -> cP); wave7 also wout(t-1) ----
    {
      v8h ah[3];
      #pragma unroll
      for (int kf = 0; kf < 3; kf++)
        ah[kf] = *(const v8h*)(c0 + mn*LDK0 + kf*32 + q8);
      v4f acc0 = {bs0a, bs0a, bs0a, bs0a};
      v4f acc1 = {bs0b, bs0b, bs0b, bs0b};
      #pragma unroll
      for (int kf = 0; kf < 3; kf++){
        acc0 = MFMAH(ah[kf], B0[kf][0], acc0);
        acc1 = MFMAH(ah[kf], B0[kf][1], acc1);
      }
      if (wv == 7 && t > 0) wout_phase(t - 1);
      #pragma unroll
      for (int r = 0; r < 4; r++){
        float v = fast_tanh(acc0[r]) * fast_tanh(acc1[r]);
        cP[(qd*4 + r)*LDK + n] = (_Float16)v;
      }
    }
    __syncthreads();  // b1

    // ---- Phase B: L1 (cP -> cQ) ----
    {
      v8h ah[4];
      #pragma unroll
      for (int kf = 0; kf < 4; kf++)
        ah[kf] = *(const v8h*)(cP + mn*LDK + kf*32 + q8);
      v4f acc0 = {bs1a, bs1a, bs1a, bs1a};
      v4f acc1 = {bs1b, bs1b, bs1b, bs1b};
      #pragma unroll
      for (int kf = 0; kf < 4; kf++){
        acc0 = MFMAH(ah[kf], B1[kf][0], acc0);
        acc1 = MFMAH(ah[kf], B1[kf][1], acc1);
      }
      #pragma unroll
      for (int r = 0; r < 4; r++){
        float v = fast_tanh(acc0[r]) * fast_tanh(acc1[r]);
        cQ[(qd*4 + r)*LDK + n] = (_Float16)v;
      }
    }
    __syncthreads();  // b2

    // ---- Phase C: L2 (cQ -> g in cGh/cGl), g = tanh(x1*x2) ----
    {
      v8h ah[4];
      #pragma unroll
      for (int kf = 0; kf < 4; kf++)
        ah[kf] = *(const v8h*)(cQ + mn*LDK + kf*32 + q8);
      v4f acc0 = {bs2a, bs2a, bs2a, bs2a};
      v4f acc1 = {bs2b, bs2b, bs2b, bs2b};
      #pragma unroll
      for (int kf = 0; kf < 4; kf++){
        acc0 = MFMAH(ah[kf], B2[kf][0], acc0);
        acc1 = MFMAH(ah[kf], B2[kf][1], acc1);
      }
      #pragma unroll
      for (int r = 0; r < 4; r++){
        float v = fast_tanh(acc0[r] * acc1[r]);
        int idx = (qd*4 + r)*LDK + n;
        _Float16 hh = (_Float16)v;
        cGh[idx] = hh;
        cGl[idx] = (_Float16)(v - (float)hh);
      }
    }
    __syncthreads();  // b3

    // ---- Phase D: wa/wb (g -> preA/preB), 3-term for precision ----
    {
      v8h gh[4], gl[4];
      #pragma unroll
      for (int kf = 0; kf < 4; kf++){
        gh[kf] = *(const v8h*)(cGh + mn*LDK + kf*32 + q8);
        gl[kf] = *(const v8h*)(cGl + mn*LDK + kf*32 + q8);
      }
      v4f p = {bsab, bsab, bsab, bsab};
      #pragma unroll
      for (int kf = 0; kf < 4; kf++){
        p = MFMAH(gh[kf], Bah[kf], p);
        p = MFMAH(gl[kf], Bah[kf], p);
        p = MFMAH(gh[kf], Bal[kf], p);
      }
      float* dst = (wv < 4) ? preA : preB;
      #pragma unroll
      for (int r = 0; r < 4; r++)
        dst[(qd*4 + r)*PRE_LD + uab] = p[r];
    }
    __syncthreads();  // b4

    // ---- Phase E: h update (fp32 regs) + alpha store + xn(t+1) ----
    {
      float nv = nrm[t & 1][es];
      float pa0 = preA[es*PRE_LD + eu],     pb0 = preB[es*PRE_LD + eu];
      float pa1 = preA[es*PRE_LD + eu + 1], pb1 = preB[es*PRE_LD + eu + 1];
      float a0 = __expf(pa0), a1 = __expf(pa1);
      float be0 = fast_tanh(pb0), be1 = fast_tanh(pb1);
      float d0 = __expf(-a0 * nv), d1 = __expf(-a1 * nv);
      h0 = d0 * (h0 - be0) + be0;
      h1 = d1 * (h1 - be1) + be1;
      c0[es*LDK0 + 8 + eu]     = (_Float16)h0;
      c0[es*LDK0 + 8 + eu + 1] = (_Float16)h1;
      float2 av = {a0, a1};
      *(float2*)(alph + ((size_t)(sgbase + es)*TB + (size_t)t)*UNITS + eu) = av;

      if (tid < 16){
        float nv2 = sqrtf(xv0*xv0 + xv1*xv1 + xv2*xv2 + xv3*xv3 + xv4*xv4 + xv5*xv5);
        nrm[(t + 1) & 1][tid] = nv2;
        float inv = 1.0f / (nv2 + EPSF);
        c0[tid*LDK0 + 0] = (_Float16)(xv0*inv);
        c0[tid*LDK0 + 1] = (_Float16)(xv1*inv);
        c0[tid*LDK0 + 2] = (_Float16)(xv2*inv);
        c0[tid*LDK0 + 3] = (_Float16)(xv3*inv);
        c0[tid*LDK0 + 4] = (_Float16)(xv4*inv);
        c0[tid*LDK0 + 5] = (_Float16)(xv5*inv);
        int tn = t + 2; if (tn > TB - 1) tn = TB - 1;
        const float* xp = x + ((size_t)(sgbase + tid)*TB + (size_t)tn)*D_IN;
        xv0 = xp[0]; xv1 = xp[1]; xv2 = xp[2]; xv3 = xp[3]; xv4 = xp[4]; xv5 = xp[5];
      }
    }
    __syncthreads();  // b5
  }

  if (wv == 7) wout_phase(TB - 1);
}

extern "C" void kernel_launch(void* const* d_in, const int* in_sizes, int n_in,
                              void* d_out, int out_size, void* d_ws, size_t ws_size,
                              hipStream_t stream) {
  const float* x    = (const float*)d_in[0];
  const float* iF   = (const float*)d_in[1];
  const float* w10  = (const float*)d_in[2];
  const float* b10  = (const float*)d_in[3];
  const float* w20  = (const float*)d_in[4];
  const float* b20  = (const float*)d_in[5];
  const float* w11  = (const float*)d_in[6];
  const float* b11  = (const float*)d_in[7];
  const float* w21  = (const float*)d_in[8];
  const float* b21  = (const float*)d_in[9];
  const float* w12  = (const float*)d_in[10];
  const float* b12  = (const float*)d_in[11];
  const float* w22  = (const float*)d_in[12];
  const float* b22  = (const float*)d_in[13];
  const float* wa   = (const float*)d_in[14];
  const float* ba   = (const float*)d_in[15];
  const float* wb   = (const float*)d_in[16];
  const float* bb   = (const float*)d_in[17];
  const float* wo   = (const float*)d_in[18];

  float* outs = (float*)d_out;
  float* alph = outs + (size_t)NB*TB*DOUT;

  lmsc_kernel<<<NB/SPB, 512, 0, stream>>>(x, iF,
      w10, b10, w20, b20, w11, b11, w21, b21, w12, b12, w22, b22,
      wa, ba, wb, bb, wo, outs, alph);
}